// Round 1
// baseline (809.804 us; speedup 1.0000x reference)
//
#include <hip/hip_runtime.h>

// Problem constants (from reference)
#define BATCH 2
#define HH 512
#define WW 512
#define NIN 64
#define NOUT 64
#define N_NZ 131072
#define N_MASK 131072
#define NPIX (BATCH * HH * WW)   // 524288

// ---------------------------------------------------------------------------
// Stage 2: mask scatter  mask[b,y,x] += mask_values[n]
// ---------------------------------------------------------------------------
__global__ void mask_scatter_kernel(const float* __restrict__ mv,
                                    const int* __restrict__ midx,
                                    float* __restrict__ mask) {
    int n = blockIdx.x * blockDim.x + threadIdx.x;
    if (n < N_MASK) {
        int b = midx[n * 3 + 0];
        int y = midx[n * 3 + 1];
        int x = midx[n * 3 + 2];
        atomicAdd(&mask[(b * HH + y) * WW + x], mv[n]);
    }
}

// ---------------------------------------------------------------------------
// Stage 3: sparse conv scatter. One wave (64 lanes) per nonzero point.
// lane = output channel. values[n,:] broadcast via LDS; 9 tap accumulators
// in registers; coalesced atomicAdd (64 consecutive floats per tap).
// ---------------------------------------------------------------------------
__global__ __launch_bounds__(64) void conv_scatter_kernel(
        const float* __restrict__ values,
        const float* __restrict__ kern,   // (3,3,NIN,NOUT) flat
        const int* __restrict__ idx,      // (N_NZ,3) int32
        float* __restrict__ dense) {      // (B,H,W,NOUT) flat, pre-zeroed
    const int n = blockIdx.x;
    const int lane = threadIdx.x;  // output channel

    __shared__ float sv[NIN];
    sv[lane] = values[n * NIN + lane];

    const int b = idx[n * 3 + 0];
    const int y = idx[n * 3 + 1];
    const int x = idx[n * 3 + 2];
    __syncthreads();

    float acc[9];
#pragma unroll
    for (int t = 0; t < 9; ++t) acc[t] = 0.0f;

    // acc[t] = sum_i sv[i] * kern[t][i][lane]
    for (int i = 0; i < NIN; ++i) {
        const float v = sv[i];
        const float* kp = kern + (size_t)i * NOUT + lane;
#pragma unroll
        for (int t = 0; t < 9; ++t) {
            acc[t] = fmaf(v, kp[(size_t)t * NIN * NOUT], acc[t]);
        }
    }

#pragma unroll
    for (int t = 0; t < 9; ++t) {
        const int ky = t / 3;
        const int kx = t % 3;
        int sy = y + ky - 1;
        int sx = x + kx - 1;
        sy = min(max(sy, 0), HH - 1);
        sx = min(max(sx, 0), WW - 1);
        const size_t off = (((size_t)b * HH + sy) * WW + sx) * NOUT + lane;
        atomicAdd(&dense[off], acc[t]);
    }
}

// ---------------------------------------------------------------------------
// Stage 4: epilogue in-place:  out[p,c] = (out[p,c] + m[p]*bias[c]) * m[p]
// One thread per 4 channels (float4).
// ---------------------------------------------------------------------------
__global__ void finalize_kernel(float* __restrict__ out,
                                const float* __restrict__ mask,
                                const float* __restrict__ bias) {
    const int t = blockIdx.x * blockDim.x + threadIdx.x;
    const int p = t >> 4;            // 16 threads per pixel (64 ch / 4)
    const int c4 = (t & 15) * 4;
    if (p < NPIX) {
        const float m = mask[p];
        float4* o = reinterpret_cast<float4*>(out + (size_t)p * NOUT + c4);
        const float4 bb = *reinterpret_cast<const float4*>(bias + c4);
        float4 v = *o;
        v.x = (v.x + m * bb.x) * m;
        v.y = (v.y + m * bb.y) * m;
        v.z = (v.z + m * bb.z) * m;
        v.w = (v.w + m * bb.w) * m;
        *o = v;
    }
}

extern "C" void kernel_launch(void* const* d_in, const int* in_sizes, int n_in,
                              void* d_out, int out_size, void* d_ws, size_t ws_size,
                              hipStream_t stream) {
    const float* values      = (const float*)d_in[0];  // (N_NZ, NIN)
    const float* kern        = (const float*)d_in[1];  // (3,3,NIN,NOUT)
    const float* bias        = (const float*)d_in[2];  // (NOUT,)
    const float* mask_values = (const float*)d_in[3];  // (N_MASK, 1)
    const int*   indices     = (const int*)d_in[4];    // (N_NZ, 3) int32
    const int*   mask_idx    = (const int*)d_in[5];    // (N_MASK, 3) int32

    float* out  = (float*)d_out;                        // (B,H,W,NOUT) fp32
    float* mask = (float*)d_ws;                         // NPIX floats scratch

    // Stage 1: zero accumulators (harness poisons d_out/d_ws with 0xAA).
    hipMemsetAsync(out, 0, (size_t)out_size * sizeof(float), stream);
    hipMemsetAsync(mask, 0, (size_t)NPIX * sizeof(float), stream);

    // Stage 2: mask scatter
    mask_scatter_kernel<<<(N_MASK + 255) / 256, 256, 0, stream>>>(mask_values, mask_idx, mask);

    // Stage 3: conv scatter (one wave per nonzero)
    conv_scatter_kernel<<<N_NZ, 64, 0, stream>>>(values, kern, indices, out);

    // Stage 4: fused epilogue
    const int total = NPIX * (NOUT / 4);
    finalize_kernel<<<(total + 255) / 256, 256, 0, stream>>>(out, mask, bias);
}

// Round 2
// 470.707 us; speedup vs baseline: 1.7204x; 1.7204x over previous
//
#include <hip/hip_runtime.h>

// Problem constants (from reference)
#define BATCH 2
#define HH 512
#define WW 512
#define NIN 64
#define NOUT 64
#define N_NZ 131072
#define N_MASK 131072
#define NPIX (BATCH * HH * WW)   // 524288
#define PPW 64                   // points per wave in conv kernel

// ---------------------------------------------------------------------------
// Mask scatter:  mask[b,y,x] += mask_values[n]
// ---------------------------------------------------------------------------
__global__ void mask_scatter_kernel(const float* __restrict__ mv,
                                    const int* __restrict__ midx,
                                    float* __restrict__ mask) {
    int n = blockIdx.x * blockDim.x + threadIdx.x;
    if (n < N_MASK) {
        int b = midx[n * 3 + 0];
        int y = midx[n * 3 + 1];
        int x = midx[n * 3 + 2];
        atomicAdd(&mask[(b * HH + y) * WW + x], mv[n]);
    }
}

// ---------------------------------------------------------------------------
// Conv scatter, register-cached kernel slice.
// One wave per (tap, tile-of-64-points). lane = output channel.
// kreg[i] = K[tap][i][lane] lives in 64 VGPRs; per point the values row is a
// wave-uniform read (scalarizes to s_load), 64 FMA, 1 coalesced atomicAdd.
// ---------------------------------------------------------------------------
__global__ __launch_bounds__(64) void conv_scatter_kernel(
        const float* __restrict__ values,   // (N_NZ, NIN)
        const float* __restrict__ kern,     // (3,3,NIN,NOUT)
        const int* __restrict__ idx,        // (N_NZ,3) int32
        float* __restrict__ dense) {        // (B,H,W,NOUT), pre-zeroed
    const int bid  = blockIdx.x;
    const int tap  = bid % 9;               // tap fast-varying: 9 taps of a
    const int tile = bid / 9;               // tile run near-concurrently
    const int lane = threadIdx.x;           // output channel
    const int ky = tap / 3;
    const int kx = tap % 3;

    // Load this tap's 64x64 kernel slice into registers (coalesced).
    float kreg[NIN];
    const float* kp = kern + (size_t)tap * NIN * NOUT + lane;
#pragma unroll
    for (int i = 0; i < NIN; ++i) kreg[i] = kp[(size_t)i * NOUT];

    const int p0 = tile * PPW;
    for (int pp = 0; pp < PPW; ++pp) {
        const int p = p0 + pp;
        // Wave-uniform loads (blockIdx/loop-derived address -> s_load).
        const int b = idx[p * 3 + 0];
        const int y = idx[p * 3 + 1];
        const int x = idx[p * 3 + 2];
        const float* vp = values + (size_t)p * NIN;

        float acc = 0.0f;
#pragma unroll
        for (int i = 0; i < NIN; ++i) acc = fmaf(vp[i], kreg[i], acc);

        int sy = min(max(y + ky - 1, 0), HH - 1);
        int sx = min(max(x + kx - 1, 0), WW - 1);
        const size_t off = (((size_t)b * HH + sy) * WW + sx) * NOUT + lane;
        atomicAdd(&dense[off], acc);  // fire-and-forget
    }
}

// ---------------------------------------------------------------------------
// Epilogue in-place: out[p,c] = (out[p,c] + m[p]*bias[c]) * m[p]
// If m==0 the result is 0 regardless of dense -> skip the read.
// 16 threads per pixel, float4 per thread.
// ---------------------------------------------------------------------------
__global__ void finalize_kernel(float* __restrict__ out,
                                const float* __restrict__ mask,
                                const float* __restrict__ bias) {
    const int t = blockIdx.x * blockDim.x + threadIdx.x;
    const int p = t >> 4;
    const int c4 = (t & 15) * 4;
    if (p >= NPIX) return;
    const float m = mask[p];
    float4* o = reinterpret_cast<float4*>(out + (size_t)p * NOUT + c4);
    if (m != 0.0f) {
        const float4 bb = *reinterpret_cast<const float4*>(bias + c4);
        float4 v = *o;
        v.x = (v.x + m * bb.x) * m;
        v.y = (v.y + m * bb.y) * m;
        v.z = (v.z + m * bb.z) * m;
        v.w = (v.w + m * bb.w) * m;
        *o = v;
    } else {
        *o = make_float4(0.f, 0.f, 0.f, 0.f);  // zero any scattered residue
    }
}

extern "C" void kernel_launch(void* const* d_in, const int* in_sizes, int n_in,
                              void* d_out, int out_size, void* d_ws, size_t ws_size,
                              hipStream_t stream) {
    const float* values      = (const float*)d_in[0];
    const float* kern        = (const float*)d_in[1];
    const float* bias        = (const float*)d_in[2];
    const float* mask_values = (const float*)d_in[3];
    const int*   indices     = (const int*)d_in[4];
    const int*   mask_idx    = (const int*)d_in[5];

    float* out  = (float*)d_out;   // (B,H,W,NOUT) fp32 — also the accumulator
    float* mask = (float*)d_ws;    // NPIX floats scratch

    hipMemsetAsync(out, 0, (size_t)out_size * sizeof(float), stream);
    hipMemsetAsync(mask, 0, (size_t)NPIX * sizeof(float), stream);

    mask_scatter_kernel<<<(N_MASK + 255) / 256, 256, 0, stream>>>(mask_values, mask_idx, mask);

    const int nblocks = 9 * (N_NZ / PPW);
    conv_scatter_kernel<<<nblocks, 64, 0, stream>>>(values, kern, indices, out);

    const int total = NPIX * (NOUT / 4);
    finalize_kernel<<<(total + 255) / 256, 256, 0, stream>>>(out, mask, bias);
}

// Round 3
// 345.595 us; speedup vs baseline: 2.3432x; 1.3620x over previous
//
#include <hip/hip_runtime.h>

// Problem constants (from reference)
#define BATCH 2
#define HH 512
#define WW 512
#define NIN 64
#define NOUT 64
#define N_NZ 131072
#define N_MASK 131072
#define NPIX (BATCH * HH * WW)   // 524288
#define PPW 64                   // points per wave in conv kernel

// ---------------------------------------------------------------------------
// Mask scatter:  mask[b,y,x] += mask_values[n]
// ---------------------------------------------------------------------------
__global__ void mask_scatter_kernel(const float* __restrict__ mv,
                                    const int* __restrict__ midx,
                                    float* __restrict__ mask) {
    int n = blockIdx.x * blockDim.x + threadIdx.x;
    if (n < N_MASK) {
        int b = midx[n * 3 + 0];
        int y = midx[n * 3 + 1];
        int x = midx[n * 3 + 2];
        atomicAdd(&mask[(b * HH + y) * WW + x], mv[n]);
    }
}

// ---------------------------------------------------------------------------
// Conv scatter, register-cached kernel slice + dead-destination skip.
// One wave per (tap, tile-of-64-points). lane = output channel.
// kreg[i] = K[tap][i][lane] in 64 VGPRs. Per point: wave-uniform idx load,
// wave-uniform mask probe at the destination pixel — if mask==0 the final
// output there is 0 regardless of dense, so skip FMA + atomic entirely.
// ---------------------------------------------------------------------------
__global__ __launch_bounds__(64) void conv_scatter_kernel(
        const float* __restrict__ values,   // (N_NZ, NIN)
        const float* __restrict__ kern,     // (3,3,NIN,NOUT)
        const int* __restrict__ idx,        // (N_NZ,3) int32
        const float* __restrict__ mask,     // (NPIX,) — already accumulated
        float* __restrict__ dense) {        // (B,H,W,NOUT), pre-zeroed
    const int bid  = blockIdx.x;
    const int tap  = bid % 9;               // tap fast-varying: 9 taps of a
    const int tile = bid / 9;               // tile share values rows in L2
    const int lane = threadIdx.x;           // output channel
    const int ky = tap / 3;
    const int kx = tap % 3;

    // Load this tap's 64x64 kernel slice into registers (L2-hot, coalesced).
    float kreg[NIN];
    const float* kp = kern + (size_t)tap * NIN * NOUT + lane;
#pragma unroll
    for (int i = 0; i < NIN; ++i) kreg[i] = kp[(size_t)i * NOUT];

    const int p0 = tile * PPW;
    for (int pp = 0; pp < PPW; ++pp) {
        const int p = p0 + pp;
        // Wave-uniform loads (blockIdx/loop-derived address -> s_load).
        const int b = idx[p * 3 + 0];
        const int y = idx[p * 3 + 1];
        const int x = idx[p * 3 + 2];

        const int sy = min(max(y + ky - 1, 0), HH - 1);
        const int sx = min(max(x + kx - 1, 0), WW - 1);
        const size_t pix = ((size_t)b * HH + sy) * WW + sx;

        // Dead-destination probe (wave-uniform, mask is 2 MB -> L2 hit).
        if (mask[pix] != 0.0f) {
            const float* vp = values + (size_t)p * NIN;
            float acc = 0.0f;
#pragma unroll
            for (int i = 0; i < NIN; ++i) acc = fmaf(vp[i], kreg[i], acc);
            atomicAdd(&dense[pix * NOUT + lane], acc);  // fire-and-forget
        }
    }
}

// ---------------------------------------------------------------------------
// Epilogue in-place: out[p,c] = (out[p,c] + m[p]*bias[c]) * m[p]
// m==0 pixels were never scattered to and are memset-zero: no touch needed.
// 16 threads per pixel, float4 per thread.
// ---------------------------------------------------------------------------
__global__ void finalize_kernel(float* __restrict__ out,
                                const float* __restrict__ mask,
                                const float* __restrict__ bias) {
    const int t = blockIdx.x * blockDim.x + threadIdx.x;
    const int p = t >> 4;
    const int c4 = (t & 15) * 4;
    if (p >= NPIX) return;
    const float m = mask[p];
    if (m == 0.0f) return;  // already zero from memset; conv skipped it too
    float4* o = reinterpret_cast<float4*>(out + (size_t)p * NOUT + c4);
    const float4 bb = *reinterpret_cast<const float4*>(bias + c4);
    float4 v = *o;
    v.x = (v.x + m * bb.x) * m;
    v.y = (v.y + m * bb.y) * m;
    v.z = (v.z + m * bb.z) * m;
    v.w = (v.w + m * bb.w) * m;
    *o = v;
}

extern "C" void kernel_launch(void* const* d_in, const int* in_sizes, int n_in,
                              void* d_out, int out_size, void* d_ws, size_t ws_size,
                              hipStream_t stream) {
    const float* values      = (const float*)d_in[0];
    const float* kern        = (const float*)d_in[1];
    const float* bias        = (const float*)d_in[2];
    const float* mask_values = (const float*)d_in[3];
    const int*   indices     = (const int*)d_in[4];
    const int*   mask_idx    = (const int*)d_in[5];

    float* out  = (float*)d_out;   // (B,H,W,NOUT) fp32 — also the accumulator
    float* mask = (float*)d_ws;    // NPIX floats scratch

    hipMemsetAsync(out, 0, (size_t)out_size * sizeof(float), stream);
    hipMemsetAsync(mask, 0, (size_t)NPIX * sizeof(float), stream);

    // Mask first — conv uses it to skip dead destinations.
    mask_scatter_kernel<<<(N_MASK + 255) / 256, 256, 0, stream>>>(mask_values, mask_idx, mask);

    const int nblocks = 9 * (N_NZ / PPW);
    conv_scatter_kernel<<<nblocks, 64, 0, stream>>>(values, kern, indices, mask, out);

    const int total = NPIX * (NOUT / 4);
    finalize_kernel<<<(total + 255) / 256, 256, 0, stream>>>(out, mask, bias);
}